// Round 1
// baseline (771.929 us; speedup 1.0000x reference)
//
#include <hip/hip_runtime.h>
#include <hip/hip_bf16.h>
#include <math.h>

#define NUM_USERS 60000
#define NUM_ITEMS 40000
#define NUM_NODES (NUM_USERS + NUM_ITEMS)
#define NNZ 2000000
#define DIM 64
#define BATCH 4096
#define TEMP_INV 5.0f   // 1/0.2

// ---------------- CSR build ----------------

__global__ void hist_kernel(const int* __restrict__ row, int* __restrict__ cnt, int nnz) {
    int stride = gridDim.x * blockDim.x;
    for (int e = blockIdx.x * blockDim.x + threadIdx.x; e < nnz; e += stride)
        atomicAdd(&cnt[row[e]], 1);
}

__global__ __launch_bounds__(1024) void scan_kernel(const int* __restrict__ cnt,
                                                    int* __restrict__ ptr, int n) {
    __shared__ int ssum[1024];
    int tid = threadIdx.x;
    const int CH = (n + 1023) / 1024;   // 98
    int base = tid * CH;
    int s = 0;
    for (int k = 0; k < CH; ++k) { int i = base + k; if (i < n) s += cnt[i]; }
    ssum[tid] = s;
    __syncthreads();
    for (int d = 1; d < 1024; d <<= 1) {
        int v = (tid >= d) ? ssum[tid - d] : 0;
        __syncthreads();
        ssum[tid] += v;
        __syncthreads();
    }
    int run = ssum[tid] - s;   // exclusive prefix of this chunk
    for (int k = 0; k < CH; ++k) {
        int i = base + k;
        if (i < n) { ptr[i] = run; run += cnt[i]; }
    }
    if (tid == 1023) ptr[n] = ssum[1023];
}

__global__ void scatter_kernel(const int* __restrict__ row, const int* __restrict__ col,
                               const float* __restrict__ val, const int* __restrict__ ptr,
                               int* __restrict__ cur, int2* __restrict__ pairs, int nnz) {
    int stride = gridDim.x * blockDim.x;
    for (int e = blockIdx.x * blockDim.x + threadIdx.x; e < nnz; e += stride) {
        int r = row[e];
        int p = atomicAdd(&cur[r], 1);
        pairs[ptr[r] + p] = make_int2(col[e], __float_as_int(val[e]));
    }
}

// ---------------- SpMM: wave per row, lane per dim ----------------

__global__ __launch_bounds__(256) void spmm_kernel(const float* __restrict__ xin,
        float* __restrict__ xout, float* __restrict__ acc,
        const int* __restrict__ ptr, const int2* __restrict__ pairs, int first) {
    int wid = (blockIdx.x * 256 + threadIdx.x) >> 6;
    int lane = threadIdx.x & 63;
    if (wid >= NUM_NODES) return;
    int s = ptr[wid], e = ptr[wid + 1];
    float a = 0.f;
    int j = s;
    for (; j + 4 <= e; j += 4) {
        int2 p0 = pairs[j], p1 = pairs[j + 1], p2 = pairs[j + 2], p3 = pairs[j + 3];
        float x0 = xin[(size_t)p0.x * DIM + lane];
        float x1 = xin[(size_t)p1.x * DIM + lane];
        float x2 = xin[(size_t)p2.x * DIM + lane];
        float x3 = xin[(size_t)p3.x * DIM + lane];
        a = fmaf(__int_as_float(p0.y), x0, a);
        a = fmaf(__int_as_float(p1.y), x1, a);
        a = fmaf(__int_as_float(p2.y), x2, a);
        a = fmaf(__int_as_float(p3.y), x3, a);
    }
    for (; j < e; ++j) {
        int2 p = pairs[j];
        a = fmaf(__int_as_float(p.y), xin[(size_t)p.x * DIM + lane], a);
    }
    size_t o = (size_t)wid * DIM + lane;
    xout[o] = a;
    if (first) acc[o] = a; else acc[o] += a;
}

// ---------------- BPR + reg ----------------

__device__ __forceinline__ float wave_sum(float v) {
    for (int o = 32; o; o >>= 1) v += __shfl_xor(v, o);
    return v;
}

__global__ __launch_bounds__(256) void loss1_kernel(const float* __restrict__ acc,
        const float* __restrict__ ut, const float* __restrict__ it,
        const int* __restrict__ user, const int* __restrict__ pos,
        const int* __restrict__ neg, float* __restrict__ oacc) {
    int lane = threadIdx.x & 63;
    int wib = threadIdx.x >> 6;
    int gw = blockIdx.x * 4 + wib;
    int nw = gridDim.x * 4;
    float sp_sum = 0.f, rg_sum = 0.f;
    for (int b = gw; b < BATCH; b += nw) {
        int iu = user[b], ip = pos[b], in_ = neg[b];
        float u = acc[(size_t)iu * DIM + lane] * (1.f / 3.f);
        float p = acc[((size_t)NUM_USERS + ip) * DIM + lane] * (1.f / 3.f);
        float n = acc[((size_t)NUM_USERS + in_) * DIM + lane] * (1.f / 3.f);
        float dp = wave_sum(u * p);
        float dn = wave_sum(u * n);
        float x = dn - dp;
        float sp = fmaxf(x, 0.f) + log1pf(expf(-fabsf(x)));
        float eu = ut[(size_t)iu * DIM + lane];
        float ep = it[(size_t)ip * DIM + lane];
        float en = it[(size_t)in_ * DIM + lane];
        float r = wave_sum(eu * eu + ep * ep + en * en);
        if (lane == 0) { sp_sum += sp; rg_sum += r; }
    }
    __shared__ float lsp[4], lrg[4];
    if (lane == 0) { lsp[wib] = sp_sum; lrg[wib] = rg_sum; }
    __syncthreads();
    if (threadIdx.x == 0) {
        atomicAdd(&oacc[0], lsp[0] + lsp[1] + lsp[2] + lsp[3]);
        atomicAdd(&oacc[1], lrg[0] + lrg[1] + lrg[2] + lrg[3]);
    }
}

// ---------------- normalize gathered rows ----------------

__global__ __launch_bounds__(256) void norm_kernel(const float* __restrict__ acc,
        const int* __restrict__ user, const int* __restrict__ pos,
        float* __restrict__ vn, float* __restrict__ posv) {
    int lane = threadIdx.x & 63;
    int gw = (blockIdx.x * 256 + threadIdx.x) >> 6;   // 0..8191
    if (gw >= 2 * BATCH) return;
    int node = (gw < BATCH) ? user[gw] : (NUM_USERS + pos[gw - BATCH]);
    float v = acc[(size_t)node * DIM + lane] * (1.f / 3.f);
    float n2 = wave_sum(v * v);
    float nrm = sqrtf(n2);
    float inv = 1.f / (nrm + 1e-8f);
    vn[(size_t)gw * DIM + lane] = v * inv;
    if (lane == 0) posv[gw] = n2 * inv * inv * TEMP_INV;
}

// ---------------- gram + fixed-shift sumexp ----------------
// 256 blocks: side (2) x j-half (2) x i-tile (64 of 64 rows).

#define GPAD 68

__global__ __launch_bounds__(256) void gram_kernel(const float* __restrict__ vn,
                                                   float* __restrict__ rowsum) {
    __shared__ float At[64][GPAD];
    __shared__ float Bt[64][GPAD];
    __shared__ float red[64][17];
    int b = blockIdx.x;
    int side = b >> 7;
    int half = (b >> 6) & 1;
    int it = b & 63;
    const float* base = vn + (size_t)side * BATCH * DIM;
    int i0 = it * 64;
    int tid = threadIdx.x;
    for (int idx = tid; idx < 4096; idx += 256) {
        int r = idx >> 6, k = idx & 63;
        At[k][r] = base[(size_t)(i0 + r) * DIM + k];
    }
    int tx = tid & 15, ty = tid >> 4;
    float accs[4] = {0.f, 0.f, 0.f, 0.f};
    for (int jt = 0; jt < 32; ++jt) {
        int j0 = half * 2048 + jt * 64;
        __syncthreads();
        for (int idx = tid; idx < 4096; idx += 256) {
            int r = idx >> 6, k = idx & 63;
            Bt[k][r] = base[(size_t)(j0 + r) * DIM + k];
        }
        __syncthreads();
        float d[4][4] = {};
        #pragma unroll 8
        for (int k = 0; k < 64; ++k) {
            float4 av = *(const float4*)&At[k][ty * 4];
            float4 bv = *(const float4*)&Bt[k][tx * 4];
            float aa[4] = {av.x, av.y, av.z, av.w};
            float bb[4] = {bv.x, bv.y, bv.z, bv.w};
            #pragma unroll
            for (int a = 0; a < 4; ++a)
                #pragma unroll
                for (int c = 0; c < 4; ++c)
                    d[a][c] = fmaf(aa[a], bb[c], d[a][c]);
        }
        #pragma unroll
        for (int a = 0; a < 4; ++a) {
            float s = 0.f;
            #pragma unroll
            for (int c = 0; c < 4; ++c)
                s += expf(d[a][c] * TEMP_INV - TEMP_INV);   // logit - 5, always <= 0
            accs[a] += s;
        }
    }
    #pragma unroll
    for (int a = 0; a < 4; ++a) red[ty * 4 + a][tx] = accs[a];
    __syncthreads();
    if (tid < 64) {
        float s = 0.f;
        #pragma unroll
        for (int c = 0; c < 16; ++c) s += red[tid][c];
        atomicAdd(&rowsum[side * BATCH + i0 + tid], s);
    }
}

__global__ __launch_bounds__(256) void lse_kernel(const float* __restrict__ rowsum,
        const float* __restrict__ posv, float* __restrict__ oacc) {
    int idx = blockIdx.x * 256 + threadIdx.x;
    float c = 0.f;
    if (idx < 2 * BATCH) {
        float s = rowsum[idx];
        c = TEMP_INV + logf(s) - posv[idx];
    }
    c = wave_sum(c);
    __shared__ float l[4];
    int lane = threadIdx.x & 63, w = threadIdx.x >> 6;
    if (lane == 0) l[w] = c;
    __syncthreads();
    if (threadIdx.x == 0) atomicAdd(&oacc[2], l[0] + l[1] + l[2] + l[3]);
}

__global__ void final_kernel(const float* __restrict__ oacc, float* __restrict__ out) {
    out[0] = oacc[0] * (1.f / BATCH);
    out[1] = oacc[1] * (1e-4f * 0.5f / BATCH);
    out[2] = oacc[2] * (0.1f / BATCH);
}

// ---------------- launch ----------------

extern "C" void kernel_launch(void* const* d_in, const int* in_sizes, int n_in,
                              void* d_out, int out_size, void* d_ws, size_t ws_size,
                              hipStream_t stream) {
    const float* user_table = (const float*)d_in[0];
    const float* item_table = (const float*)d_in[1];
    const float* edge_val   = (const float*)d_in[2];
    const int*   user       = (const int*)d_in[3];
    const int*   positive   = (const int*)d_in[4];
    const int*   negative   = (const int*)d_in[5];
    const int*   edge_row   = (const int*)d_in[6];
    const int*   edge_col   = (const int*)d_in[7];
    float* out = (float*)d_out;

    char* w = (char*)d_ws;
    auto alloc = [&](size_t bytes) {
        char* p = w;
        w += (bytes + 255) & ~(size_t)255;
        return p;
    };
    int*   row_ptr = (int*)alloc((NUM_NODES + 1) * sizeof(int));
    int*   cursor  = (int*)alloc(NUM_NODES * sizeof(int));
    int2*  pairs   = (int2*)alloc((size_t)NNZ * sizeof(int2));
    float* xA      = (float*)alloc((size_t)NUM_NODES * DIM * sizeof(float));
    float* xB      = (float*)alloc((size_t)NUM_NODES * DIM * sizeof(float));
    float* acc     = (float*)alloc((size_t)NUM_NODES * DIM * sizeof(float));
    float* vn      = (float*)alloc((size_t)2 * BATCH * DIM * sizeof(float));
    float* posv    = (float*)alloc(2 * BATCH * sizeof(float));
    float* rowsum  = (float*)alloc(2 * BATCH * sizeof(float));
    float* oacc    = (float*)alloc(4 * sizeof(float));

    hipMemsetAsync(cursor, 0, NUM_NODES * sizeof(int), stream);
    hipMemsetAsync(oacc, 0, 4 * sizeof(float), stream);
    hipMemsetAsync(rowsum, 0, 2 * BATCH * sizeof(float), stream);

    hist_kernel<<<2048, 256, 0, stream>>>(edge_row, cursor, NNZ);
    scan_kernel<<<1, 1024, 0, stream>>>(cursor, row_ptr, NUM_NODES);
    hipMemsetAsync(cursor, 0, NUM_NODES * sizeof(int), stream);
    scatter_kernel<<<2048, 256, 0, stream>>>(edge_row, edge_col, edge_val,
                                             row_ptr, cursor, pairs, NNZ);

    hipMemcpyAsync(xA, user_table, (size_t)NUM_USERS * DIM * sizeof(float),
                   hipMemcpyDeviceToDevice, stream);
    hipMemcpyAsync(xA + (size_t)NUM_USERS * DIM, item_table,
                   (size_t)NUM_ITEMS * DIM * sizeof(float),
                   hipMemcpyDeviceToDevice, stream);

    const int SPMM_BLOCKS = (NUM_NODES + 3) / 4;   // 4 waves (rows) per 256-thr block
    spmm_kernel<<<SPMM_BLOCKS, 256, 0, stream>>>(xA, xB, acc, row_ptr, pairs, 1);
    spmm_kernel<<<SPMM_BLOCKS, 256, 0, stream>>>(xB, xA, acc, row_ptr, pairs, 0);
    spmm_kernel<<<SPMM_BLOCKS, 256, 0, stream>>>(xA, xB, acc, row_ptr, pairs, 0);

    loss1_kernel<<<256, 256, 0, stream>>>(acc, user_table, item_table,
                                          user, positive, negative, oacc);
    norm_kernel<<<(2 * BATCH) / 4, 256, 0, stream>>>(acc, user, positive, vn, posv);
    gram_kernel<<<256, 256, 0, stream>>>(vn, rowsum);
    lse_kernel<<<(2 * BATCH + 255) / 256, 256, 0, stream>>>(rowsum, posv, oacc);
    final_kernel<<<1, 1, 0, stream>>>(oacc, out);
}

// Round 2
// 528.480 us; speedup vs baseline: 1.4607x; 1.4607x over previous
//
#include <hip/hip_runtime.h>
#include <hip/hip_bf16.h>
#include <math.h>

#define NUM_USERS 60000
#define NUM_ITEMS 40000
#define NUM_NODES (NUM_USERS + NUM_ITEMS)
#define NNZ 2000000
#define DIM 64
#define BATCH 4096
#define TEMP_INV 5.0f   // 1/0.2
#define SCAN_BLOCKS ((NUM_NODES + 1023) / 1024)   // 98

// ---------------- CSR build ----------------

__global__ void hist_kernel(const int* __restrict__ row, int* __restrict__ cnt,
                            int* __restrict__ rank, int nnz) {
    int stride = gridDim.x * blockDim.x;
    for (int e = blockIdx.x * blockDim.x + threadIdx.x; e < nnz; e += stride)
        rank[e] = atomicAdd(&cnt[row[e]], 1);
}

// multi-block scan: per-block local exclusive scan + block sums
__global__ __launch_bounds__(1024) void scan1_kernel(const int* __restrict__ cnt,
        int* __restrict__ ptr, int* __restrict__ bsum, int n) {
    __shared__ int sh[1024];
    int t = threadIdx.x;
    int i = blockIdx.x * 1024 + t;
    int v = (i < n) ? cnt[i] : 0;
    sh[t] = v;
    __syncthreads();
    for (int d = 1; d < 1024; d <<= 1) {
        int w = (t >= d) ? sh[t - d] : 0;
        __syncthreads();
        sh[t] += w;
        __syncthreads();
    }
    int incl = sh[t];
    if (i < n) ptr[i] = incl - v;          // local exclusive
    if (t == 1023) bsum[blockIdx.x] = incl;
}

__global__ __launch_bounds__(128) void scan2_kernel(const int* __restrict__ bsum,
        int* __restrict__ boffs, int* __restrict__ ptr, int nb, int n) {
    __shared__ int sh[128];
    int t = threadIdx.x;
    int v = (t < nb) ? bsum[t] : 0;
    sh[t] = v;
    __syncthreads();
    for (int d = 1; d < 128; d <<= 1) {
        int w = (t >= d) ? sh[t - d] : 0;
        __syncthreads();
        sh[t] += w;
        __syncthreads();
    }
    if (t < nb) boffs[t] = sh[t] - v;      // exclusive block offset
    if (t == 127) ptr[n] = sh[127];        // grand total (== NNZ)
}

__global__ __launch_bounds__(1024) void scan3_kernel(int* __restrict__ ptr,
        const int* __restrict__ boffs, int n) {
    int i = blockIdx.x * 1024 + threadIdx.x;
    if (i < n) ptr[i] += boffs[blockIdx.x];
}

// atomic-free scatter using precomputed ranks
__global__ void scatter_kernel(const int* __restrict__ row, const int* __restrict__ col,
                               const float* __restrict__ val, const int* __restrict__ ptr,
                               const int* __restrict__ rank, int2* __restrict__ pairs,
                               int nnz) {
    int stride = gridDim.x * blockDim.x;
    for (int e = blockIdx.x * blockDim.x + threadIdx.x; e < nnz; e += stride)
        pairs[ptr[row[e]] + rank[e]] = make_int2(col[e], __float_as_int(val[e]));
}

// ---------------- SpMM: wave per row, lane per dim ----------------

__global__ __launch_bounds__(256) void spmm_kernel(const float* __restrict__ xin,
        float* __restrict__ xout, float* __restrict__ acc,
        const int* __restrict__ ptr, const int2* __restrict__ pairs, int first) {
    int wid = (blockIdx.x * 256 + threadIdx.x) >> 6;
    int lane = threadIdx.x & 63;
    if (wid >= NUM_NODES) return;
    int s = ptr[wid], e = ptr[wid + 1];
    float a = 0.f;
    int j = s;
    for (; j + 4 <= e; j += 4) {
        int2 p0 = pairs[j], p1 = pairs[j + 1], p2 = pairs[j + 2], p3 = pairs[j + 3];
        float x0 = xin[(size_t)p0.x * DIM + lane];
        float x1 = xin[(size_t)p1.x * DIM + lane];
        float x2 = xin[(size_t)p2.x * DIM + lane];
        float x3 = xin[(size_t)p3.x * DIM + lane];
        a = fmaf(__int_as_float(p0.y), x0, a);
        a = fmaf(__int_as_float(p1.y), x1, a);
        a = fmaf(__int_as_float(p2.y), x2, a);
        a = fmaf(__int_as_float(p3.y), x3, a);
    }
    for (; j < e; ++j) {
        int2 p = pairs[j];
        a = fmaf(__int_as_float(p.y), xin[(size_t)p.x * DIM + lane], a);
    }
    size_t o = (size_t)wid * DIM + lane;
    xout[o] = a;
    if (first) acc[o] = a; else acc[o] += a;
}

// ---------------- BPR + reg ----------------

__device__ __forceinline__ float wave_sum(float v) {
    for (int o = 32; o; o >>= 1) v += __shfl_xor(v, o);
    return v;
}

__global__ __launch_bounds__(256) void loss1_kernel(const float* __restrict__ acc,
        const float* __restrict__ ut, const float* __restrict__ it,
        const int* __restrict__ user, const int* __restrict__ pos,
        const int* __restrict__ neg, float* __restrict__ oacc) {
    int lane = threadIdx.x & 63;
    int wib = threadIdx.x >> 6;
    int gw = blockIdx.x * 4 + wib;
    int nw = gridDim.x * 4;
    float sp_sum = 0.f, rg_sum = 0.f;
    for (int b = gw; b < BATCH; b += nw) {
        int iu = user[b], ip = pos[b], in_ = neg[b];
        float u = acc[(size_t)iu * DIM + lane] * (1.f / 3.f);
        float p = acc[((size_t)NUM_USERS + ip) * DIM + lane] * (1.f / 3.f);
        float n = acc[((size_t)NUM_USERS + in_) * DIM + lane] * (1.f / 3.f);
        float dp = wave_sum(u * p);
        float dn = wave_sum(u * n);
        float x = dn - dp;
        float sp = fmaxf(x, 0.f) + log1pf(expf(-fabsf(x)));
        float eu = ut[(size_t)iu * DIM + lane];
        float ep = it[(size_t)ip * DIM + lane];
        float en = it[(size_t)in_ * DIM + lane];
        float r = wave_sum(eu * eu + ep * ep + en * en);
        if (lane == 0) { sp_sum += sp; rg_sum += r; }
    }
    __shared__ float lsp[4], lrg[4];
    if (lane == 0) { lsp[wib] = sp_sum; lrg[wib] = rg_sum; }
    __syncthreads();
    if (threadIdx.x == 0) {
        atomicAdd(&oacc[0], lsp[0] + lsp[1] + lsp[2] + lsp[3]);
        atomicAdd(&oacc[1], lrg[0] + lrg[1] + lrg[2] + lrg[3]);
    }
}

// ---------------- normalize gathered rows ----------------

__global__ __launch_bounds__(256) void norm_kernel(const float* __restrict__ acc,
        const int* __restrict__ user, const int* __restrict__ pos,
        float* __restrict__ vn, float* __restrict__ posv) {
    int lane = threadIdx.x & 63;
    int gw = (blockIdx.x * 256 + threadIdx.x) >> 6;   // 0..8191
    if (gw >= 2 * BATCH) return;
    int node = (gw < BATCH) ? user[gw] : (NUM_USERS + pos[gw - BATCH]);
    float v = acc[(size_t)node * DIM + lane] * (1.f / 3.f);
    float n2 = wave_sum(v * v);
    float nrm = sqrtf(n2);
    float inv = 1.f / (nrm + 1e-8f);
    vn[(size_t)gw * DIM + lane] = v * inv;
    if (lane == 0) posv[gw] = n2 * inv * inv * TEMP_INV;
}

// ---------------- gram + fixed-shift sumexp ----------------
// 256 blocks: side (2) x j-half (2) x i-tile (64 of 64 rows).

#define GPAD 68

__global__ __launch_bounds__(256) void gram_kernel(const float* __restrict__ vn,
                                                   float* __restrict__ rowsum) {
    __shared__ float At[64][GPAD];
    __shared__ float Bt[64][GPAD];
    __shared__ float red[64][17];
    int b = blockIdx.x;
    int side = b >> 7;
    int half = (b >> 6) & 1;
    int it = b & 63;
    const float* base = vn + (size_t)side * BATCH * DIM;
    int i0 = it * 64;
    int tid = threadIdx.x;
    for (int idx = tid; idx < 4096; idx += 256) {
        int r = idx >> 6, k = idx & 63;
        At[k][r] = base[(size_t)(i0 + r) * DIM + k];
    }
    int tx = tid & 15, ty = tid >> 4;
    float accs[4] = {0.f, 0.f, 0.f, 0.f};
    for (int jt = 0; jt < 32; ++jt) {
        int j0 = half * 2048 + jt * 64;
        __syncthreads();
        for (int idx = tid; idx < 4096; idx += 256) {
            int r = idx >> 6, k = idx & 63;
            Bt[k][r] = base[(size_t)(j0 + r) * DIM + k];
        }
        __syncthreads();
        float d[4][4] = {};
        #pragma unroll 8
        for (int k = 0; k < 64; ++k) {
            float4 av = *(const float4*)&At[k][ty * 4];
            float4 bv = *(const float4*)&Bt[k][tx * 4];
            float aa[4] = {av.x, av.y, av.z, av.w};
            float bb[4] = {bv.x, bv.y, bv.z, bv.w};
            #pragma unroll
            for (int a = 0; a < 4; ++a)
                #pragma unroll
                for (int c = 0; c < 4; ++c)
                    d[a][c] = fmaf(aa[a], bb[c], d[a][c]);
        }
        #pragma unroll
        for (int a = 0; a < 4; ++a) {
            float s = 0.f;
            #pragma unroll
            for (int c = 0; c < 4; ++c)
                s += expf(d[a][c] * TEMP_INV - TEMP_INV);   // logit - 5, always <= 0
            accs[a] += s;
        }
    }
    #pragma unroll
    for (int a = 0; a < 4; ++a) red[ty * 4 + a][tx] = accs[a];
    __syncthreads();
    if (tid < 64) {
        float s = 0.f;
        #pragma unroll
        for (int c = 0; c < 16; ++c) s += red[tid][c];
        atomicAdd(&rowsum[side * BATCH + i0 + tid], s);
    }
}

__global__ __launch_bounds__(256) void lse_kernel(const float* __restrict__ rowsum,
        const float* __restrict__ posv, float* __restrict__ oacc) {
    int idx = blockIdx.x * 256 + threadIdx.x;
    float c = 0.f;
    if (idx < 2 * BATCH) {
        float s = rowsum[idx];
        c = TEMP_INV + logf(s) - posv[idx];
    }
    c = wave_sum(c);
    __shared__ float l[4];
    int lane = threadIdx.x & 63, w = threadIdx.x >> 6;
    if (lane == 0) l[w] = c;
    __syncthreads();
    if (threadIdx.x == 0) atomicAdd(&oacc[2], l[0] + l[1] + l[2] + l[3]);
}

__global__ void final_kernel(const float* __restrict__ oacc, float* __restrict__ out) {
    out[0] = oacc[0] * (1.f / BATCH);
    out[1] = oacc[1] * (1e-4f * 0.5f / BATCH);
    out[2] = oacc[2] * (0.1f / BATCH);
}

// ---------------- launch ----------------

extern "C" void kernel_launch(void* const* d_in, const int* in_sizes, int n_in,
                              void* d_out, int out_size, void* d_ws, size_t ws_size,
                              hipStream_t stream) {
    const float* user_table = (const float*)d_in[0];
    const float* item_table = (const float*)d_in[1];
    const float* edge_val   = (const float*)d_in[2];
    const int*   user       = (const int*)d_in[3];
    const int*   positive   = (const int*)d_in[4];
    const int*   negative   = (const int*)d_in[5];
    const int*   edge_row   = (const int*)d_in[6];
    const int*   edge_col   = (const int*)d_in[7];
    float* out = (float*)d_out;

    char* w = (char*)d_ws;
    auto alloc = [&](size_t bytes) {
        char* p = w;
        w += (bytes + 255) & ~(size_t)255;
        return p;
    };
    int*   row_ptr = (int*)alloc((NUM_NODES + 1) * sizeof(int));
    int*   cnt     = (int*)alloc(NUM_NODES * sizeof(int));
    int*   rank    = (int*)alloc((size_t)NNZ * sizeof(int));
    int*   bsum    = (int*)alloc(SCAN_BLOCKS * sizeof(int));
    int*   boffs   = (int*)alloc(SCAN_BLOCKS * sizeof(int));
    int2*  pairs   = (int2*)alloc((size_t)NNZ * sizeof(int2));
    float* xA      = (float*)alloc((size_t)NUM_NODES * DIM * sizeof(float));
    float* xB      = (float*)alloc((size_t)NUM_NODES * DIM * sizeof(float));
    float* acc     = (float*)alloc((size_t)NUM_NODES * DIM * sizeof(float));
    float* vn      = (float*)alloc((size_t)2 * BATCH * DIM * sizeof(float));
    float* posv    = (float*)alloc(2 * BATCH * sizeof(float));
    float* rowsum  = (float*)alloc(2 * BATCH * sizeof(float));
    float* oacc    = (float*)alloc(4 * sizeof(float));

    hipMemsetAsync(cnt, 0, NUM_NODES * sizeof(int), stream);
    hipMemsetAsync(oacc, 0, 4 * sizeof(float), stream);
    hipMemsetAsync(rowsum, 0, 2 * BATCH * sizeof(float), stream);

    hist_kernel<<<2048, 256, 0, stream>>>(edge_row, cnt, rank, NNZ);
    scan1_kernel<<<SCAN_BLOCKS, 1024, 0, stream>>>(cnt, row_ptr, bsum, NUM_NODES);
    scan2_kernel<<<1, 128, 0, stream>>>(bsum, boffs, row_ptr, SCAN_BLOCKS, NUM_NODES);
    scan3_kernel<<<SCAN_BLOCKS, 1024, 0, stream>>>(row_ptr, boffs, NUM_NODES);
    scatter_kernel<<<2048, 256, 0, stream>>>(edge_row, edge_col, edge_val,
                                             row_ptr, rank, pairs, NNZ);

    hipMemcpyAsync(xA, user_table, (size_t)NUM_USERS * DIM * sizeof(float),
                   hipMemcpyDeviceToDevice, stream);
    hipMemcpyAsync(xA + (size_t)NUM_USERS * DIM, item_table,
                   (size_t)NUM_ITEMS * DIM * sizeof(float),
                   hipMemcpyDeviceToDevice, stream);

    const int SPMM_BLOCKS = (NUM_NODES + 3) / 4;   // 4 waves (rows) per 256-thr block
    spmm_kernel<<<SPMM_BLOCKS, 256, 0, stream>>>(xA, xB, acc, row_ptr, pairs, 1);
    spmm_kernel<<<SPMM_BLOCKS, 256, 0, stream>>>(xB, xA, acc, row_ptr, pairs, 0);
    spmm_kernel<<<SPMM_BLOCKS, 256, 0, stream>>>(xA, xB, acc, row_ptr, pairs, 0);

    loss1_kernel<<<256, 256, 0, stream>>>(acc, user_table, item_table,
                                          user, positive, negative, oacc);
    norm_kernel<<<(2 * BATCH) / 4, 256, 0, stream>>>(acc, user, positive, vn, posv);
    gram_kernel<<<256, 256, 0, stream>>>(vn, rowsum);
    lse_kernel<<<(2 * BATCH + 255) / 256, 256, 0, stream>>>(rowsum, posv, oacc);
    final_kernel<<<1, 1, 0, stream>>>(oacc, out);
}